// Round 3
// baseline (154.018 us; speedup 1.0000x reference)
//
#include <hip/hip_runtime.h>

// FSAF target assignment, MI355X.
// Output layout (f32, concatenated): cls_t (16,21824,80) | cls_m (16,21824) |
// num_pos (16,) | reg_t (16,21824,4) | reg_m (16,21824)
//
// R3 structure: cls_t zeros (111.7 MB, 93% of output bytes) are delegated to
// hipMemsetAsync (rocclr fill sustains 6.5 TB/s); the compute kernel writes
// only masks + reg targets (8.4 MB) + ~700 sparse one-hot 1.0f scatters,
// stream-ordered after the memset.

#define NPIX      21824
#define NBOX      64
#define BATCH     16
#define BIG_AREA  10000000.0f

#define CLSM_OFF  27934720          // 16*21824*80
#define NUMP_OFF  28283904          // CLSM_OFF + 16*21824
#define REGT_OFF  28283920          // NUMP_OFF + 16
#define REGM_OFF  29680656          // REGT_OFF + 16*21824*4
// REGT_OFF/4 = 7070980  (float4-aligned)

__device__ __forceinline__ void prop_box(float x1, float y1, float x2, float y2,
                                         float a, float fwf,
                                         int& ox1, int& oy1, int& ox2, int& oy2) {
    // Match numpy exactly: block FMA contraction with _rn intrinsics.
    float w = __fsub_rn(x2, x1);
    float h = __fsub_rn(y2, y1);
    float nx1 = floorf(__fadd_rn(x1, __fmul_rn(a, w)));
    float ny1 = floorf(__fadd_rn(y1, __fmul_rn(a, h)));
    float nx2 = ceilf(__fsub_rn(x2, __fmul_rn(a, w)));
    float ny2 = ceilf(__fsub_rn(y2, __fmul_rn(a, h)));
    nx2 = fminf(fmaxf(fmaxf(nx2, __fadd_rn(nx1, 1.0f)), 0.0f), fwf);
    ny2 = fminf(fmaxf(fmaxf(ny2, __fadd_rn(ny1, 1.0f)), 0.0f), fwf);
    nx1 = fminf(fmaxf(nx1, 0.0f), fwf - 1.0f);
    ny1 = fminf(fmaxf(ny1, 0.0f), fwf - 1.0f);
    ox1 = (int)nx1; oy1 = (int)ny1; ox2 = (int)nx2; oy2 = (int)ny2;
}

__global__ __launch_bounds__(256) void fsaf_kernel(const int* __restrict__ levels,
                                                   const float* __restrict__ gt,
                                                   float* __restrict__ out) {
    const int img = blockIdx.y;
    const int bx  = blockIdx.x;          // 0..85 — each block inside one level
    const int tid = threadIdx.x;

    int level, loff, fwl;
    if      (bx < 64) { level = 0; loff = 0;     fwl = 7; }   // 128x128
    else if (bx < 80) { level = 1; loff = 16384; fwl = 6; }   // 64x64
    else if (bx < 84) { level = 2; loff = 20480; fwl = 5; }   // 32x32
    else if (bx == 84){ level = 3; loff = 21504; fwl = 4; }   // 16x16
    else              { level = 4; loff = 21760; fwl = 3; }   // 8x8 (64 px)

    const int    fw      = 1 << fwl;
    const float  stride  = (float)(8 << level);
    const int    pixBase = bx << 8;
    const int    numPix  = min(256, NPIX - pixBase);
    const size_t imgBase = (size_t)img * NPIX;

    // ---- wave-0: per-box prop rects + tile-row intersection compaction.
    __shared__ int4   s_pos[NBOX];     // compacted pos rect (x1,y1,x2,y2)
    __shared__ int4   s_ign[NBOX];     // compacted ignore rect (superset of pos)
    __shared__ float  s_area[NBOX];
    __shared__ float4 s_box[NBOX];     // image-coord box for regr target
    __shared__ int    s_lab[NBOX];
    __shared__ int    s_cnt;

    if (tid < NBOX) {
        const float* g = gt + (size_t)(img * NBOX + tid) * 5;
        float b0 = g[0], b1 = g[1], b2 = g[2], b3 = g[3];
        int   lab   = (int)g[4];
        bool  valid = (levels[img * NBOX + tid] == level);

        const float inv = 1.0f / stride;              // pow2 -> exact
        float px1 = b0 * inv, py1 = b1 * inv, px2 = b2 * inv, py2 = b3 * inv;
        const float fwf = (float)fw;

        int pa, pb, pc, pd, ia, ib, ic, id;
        prop_box(px1, py1, px2, py2, 0.4f,  fwf, pa, pb, pc, pd);  // POS_SCALE=0.2
        prop_box(px1, py1, px2, py2, 0.25f, fwf, ia, ib, ic, id);  // IGNORE_SCALE=0.5

        // tile = full-width rows [y0, yEnd); ignore-rect row test (pos ⊆ ign)
        int y0   = (pixBase - loff) >> fwl;
        int yEnd = y0 + (numPix >> fwl);
        bool hit = valid && (ib < yEnd) && (id > y0);

        unsigned long long m = __ballot(hit);         // wave 0 only
        if (hit) {
            int idx = __popcll(m & ((1ull << tid) - 1ull));  // order-preserving
            s_pos[idx]  = make_int4(pa, pb, pc, pd);
            s_ign[idx]  = make_int4(ia, ib, ic, id);
            s_area[idx] = (b2 - b0) * (b3 - b1);      // sub,sub,mul — no FMA risk
            s_box[idx]  = make_float4(b0, b1, b2, b3);
            s_lab[idx]  = lab;
        }
        if (tid == 0) s_cnt = __popcll(m);
    }
    __syncthreads();

    // ---- per-pixel scan over the (short) compacted list.
    const int  p      = pixBase + tid;
    const bool active = tid < numPix;
    const int  local  = p - loff;
    const int  y      = local >> fwl;
    const int  x      = local & (fw - 1);

    float best   = BIG_AREA;
    int   chosen = 0;
    bool  anyIgn = false;
    const int cnt = s_cnt;
    for (int n = 0; n < cnt; ++n) {
        int4 ig = s_ign[n];
        bool ing = (y >= ig.y) & (y < ig.w) & (x >= ig.x) & (x < ig.z);
        anyIgn |= ing;
        int4 ps = s_pos[n];
        bool inp = (y >= ps.y) & (y < ps.w) & (x >= ps.x) & (x < ps.z);
        float am = inp ? s_area[n] : BIG_AREA;
        bool better = am < best;                      // strict '<' = first-min
        best   = better ? am : best;
        chosen = better ? n  : chosen;
    }
    const bool anyPos = best < BIG_AREA;

    if (active) {
        out[CLSM_OFF + imgBase + p] = (anyPos || !anyIgn) ? 1.0f : 0.0f;
        out[REGM_OFF + imgBase + p] = anyPos ? 1.0f : 0.0f;

        float4 rt = {0.f, 0.f, 0.f, 0.f};
        if (anyPos) {
            float4 cb = s_box[chosen];
            float sx = ((float)x + 0.5f) * stride;    // exact
            float sy = ((float)y + 0.5f) * stride;
            rt.x = (sx - cb.x) * 0.25f;
            rt.y = (sy - cb.y) * 0.25f;
            rt.z = (cb.z - sx) * 0.25f;
            rt.w = (cb.w - sy) * 0.25f;
            // sparse one-hot scatter; zeros were laid down by the stream-ordered
            // hipMemsetAsync before this kernel.
            out[(imgBase + p) * 80 + s_lab[chosen]] = 1.0f;
        }
        ((float4*)out)[(size_t)REGT_OFF / 4 + imgBase + p] = rt;
    }

    // ---- num_pos: per-wave ballot + one float atomic per wave.
    unsigned long long bal = __ballot(active && anyPos);
    if ((tid & 63) == 0) {
        int c = __popcll(bal);
        if (c) atomicAdd(out + NUMP_OFF + img, (float)c);
    }
}

extern "C" void kernel_launch(void* const* d_in, const int* in_sizes, int n_in,
                              void* d_out, int out_size, void* d_ws, size_t ws_size,
                              hipStream_t stream) {
    const int*   levels = (const int*)d_in[0];    // (16,64) int32
    const float* gt     = (const float*)d_in[1];  // (16,64,5) f32
    float*       out    = (float*)d_out;

    // Zero cls_t (111.7 MB) with the tuned rocclr fill — 6.5 TB/s measured.
    hipMemsetAsync(d_out, 0, (size_t)CLSM_OFF * sizeof(float), stream);
    // Zero the 16 num_pos accumulators.
    hipMemsetAsync((char*)d_out + (size_t)NUMP_OFF * sizeof(float), 0,
                   BATCH * sizeof(float), stream);

    dim3 grid(86, BATCH);
    fsaf_kernel<<<grid, 256, 0, stream>>>(levels, gt, out);
}

// Round 5
// 144.515 us; speedup vs baseline: 1.0658x; 1.0658x over previous
//
#include <hip/hip_runtime.h>

// FSAF target assignment, MI355X.
// Output layout (f32, concatenated): cls_t (16,21824,80) | cls_m (16,21824) |
// num_pos (16,) | reg_t (16,21824,4) | reg_m (16,21824)
//
// R5 = R4 with clang-native vector type for nontemporal 16-B stores
// (__builtin_nontemporal_store rejects HIP_vector_type float4).

#define NPIX      21824
#define NBOX      64
#define BATCH     16
#define BIG_AREA  10000000.0f

#define CLSM_OFF  27934720          // 16*21824*80
#define NUMP_OFF  28283904          // CLSM_OFF + 16*21824
#define REGT_OFF  28283920          // NUMP_OFF + 16
#define REGM_OFF  29680656          // REGT_OFF + 16*21824*4
// REGT_OFF/4 = 7070980  (float4-aligned)

typedef float f32x4 __attribute__((ext_vector_type(4)));

__device__ __forceinline__ void prop_box(float x1, float y1, float x2, float y2,
                                         float a, float fwf,
                                         int& ox1, int& oy1, int& ox2, int& oy2) {
    // Match numpy exactly: block FMA contraction with _rn intrinsics.
    float w = __fsub_rn(x2, x1);
    float h = __fsub_rn(y2, y1);
    float nx1 = floorf(__fadd_rn(x1, __fmul_rn(a, w)));
    float ny1 = floorf(__fadd_rn(y1, __fmul_rn(a, h)));
    float nx2 = ceilf(__fsub_rn(x2, __fmul_rn(a, w)));
    float ny2 = ceilf(__fsub_rn(y2, __fmul_rn(a, h)));
    nx2 = fminf(fmaxf(fmaxf(nx2, __fadd_rn(nx1, 1.0f)), 0.0f), fwf);
    ny2 = fminf(fmaxf(fmaxf(ny2, __fadd_rn(ny1, 1.0f)), 0.0f), fwf);
    nx1 = fminf(fmaxf(nx1, 0.0f), fwf - 1.0f);
    ny1 = fminf(fmaxf(ny1, 0.0f), fwf - 1.0f);
    ox1 = (int)nx1; oy1 = (int)ny1; ox2 = (int)nx2; oy2 = (int)ny2;
}

__global__ __launch_bounds__(256) void fsaf_kernel(const int* __restrict__ levels,
                                                   const float* __restrict__ gt,
                                                   float* __restrict__ out) {
    const int img = blockIdx.y;
    const int bx  = blockIdx.x;          // 0..85 — each block inside one level
    const int tid = threadIdx.x;

    int level, loff, fwl;
    if      (bx < 64) { level = 0; loff = 0;     fwl = 7; }   // 128x128
    else if (bx < 80) { level = 1; loff = 16384; fwl = 6; }   // 64x64
    else if (bx < 84) { level = 2; loff = 20480; fwl = 5; }   // 32x32
    else if (bx == 84){ level = 3; loff = 21504; fwl = 4; }   // 16x16
    else              { level = 4; loff = 21760; fwl = 3; }   // 8x8 (64 px)

    const int    fw      = 1 << fwl;
    const float  stride  = (float)(8 << level);
    const int    pixBase = bx << 8;
    const int    numPix  = min(256, NPIX - pixBase);
    const size_t imgBase = (size_t)img * NPIX;

    // ---- 1. cls_target zero-fill: coalesced nontemporal dwordx4 stream.
    f32x4* cls4 = (f32x4*)out;
    const size_t base4  = (imgBase + (size_t)pixBase) * 20;
    const int    total4 = numPix * 20;
    const f32x4 z4 = {0.f, 0.f, 0.f, 0.f};
    #pragma unroll 4
    for (int f = tid; f < total4; f += 256)
        __builtin_nontemporal_store(z4, &cls4[base4 + f]);

    // ---- 2. wave-0: per-box prop rects + tile-row intersection compaction.
    __shared__ int4   s_pos[NBOX];     // compacted pos rect (x1,y1,x2,y2)
    __shared__ int4   s_ign[NBOX];     // compacted ignore rect (superset of pos)
    __shared__ float  s_area[NBOX];
    __shared__ float4 s_box[NBOX];     // image-coord box for regr target
    __shared__ int    s_lab[NBOX];
    __shared__ int    s_cnt;

    if (tid < NBOX) {
        const float* g = gt + (size_t)(img * NBOX + tid) * 5;
        float b0 = g[0], b1 = g[1], b2 = g[2], b3 = g[3];
        int   lab   = (int)g[4];
        bool  valid = (levels[img * NBOX + tid] == level);

        const float inv = 1.0f / stride;              // pow2 -> exact
        float px1 = b0 * inv, py1 = b1 * inv, px2 = b2 * inv, py2 = b3 * inv;
        const float fwf = (float)fw;

        int pa, pb, pc, pd, ia, ib, ic, id;
        prop_box(px1, py1, px2, py2, 0.4f,  fwf, pa, pb, pc, pd);  // POS_SCALE=0.2
        prop_box(px1, py1, px2, py2, 0.25f, fwf, ia, ib, ic, id);  // IGNORE_SCALE=0.5

        // tile = full-width rows [y0, yEnd); ignore-rect row test (pos ⊆ ign)
        int y0   = (pixBase - loff) >> fwl;
        int yEnd = y0 + (numPix >> fwl);
        bool hit = valid && (ib < yEnd) && (id > y0);

        unsigned long long m = __ballot(hit);         // wave 0 only
        if (hit) {
            int idx = __popcll(m & ((1ull << tid) - 1ull));  // order-preserving
            s_pos[idx]  = make_int4(pa, pb, pc, pd);
            s_ign[idx]  = make_int4(ia, ib, ic, id);
            s_area[idx] = (b2 - b0) * (b3 - b1);      // sub,sub,mul — no FMA risk
            s_box[idx]  = make_float4(b0, b1, b2, b3);
            s_lab[idx]  = lab;
        }
        if (tid == 0) s_cnt = __popcll(m);
    }
    __syncthreads();   // also drains vmcnt(0): zero-fill globally visible

    // ---- 3. per-pixel scan over the (short) compacted list.
    const int  p      = pixBase + tid;
    const bool active = tid < numPix;
    const int  local  = p - loff;
    const int  y      = local >> fwl;
    const int  x      = local & (fw - 1);

    float best   = BIG_AREA;
    int   chosen = 0;
    bool  anyIgn = false;
    const int cnt = s_cnt;
    for (int n = 0; n < cnt; ++n) {
        int4 ig = s_ign[n];
        bool ing = (y >= ig.y) & (y < ig.w) & (x >= ig.x) & (x < ig.z);
        anyIgn |= ing;
        int4 ps = s_pos[n];
        bool inp = (y >= ps.y) & (y < ps.w) & (x >= ps.x) & (x < ps.z);
        float am = inp ? s_area[n] : BIG_AREA;
        bool better = am < best;                      // strict '<' = first-min
        best   = better ? am : best;
        chosen = better ? n  : chosen;
    }
    const bool anyPos = best < BIG_AREA;

    if (active) {
        __builtin_nontemporal_store((anyPos || !anyIgn) ? 1.0f : 0.0f,
                                    &out[CLSM_OFF + imgBase + p]);
        __builtin_nontemporal_store(anyPos ? 1.0f : 0.0f,
                                    &out[REGM_OFF + imgBase + p]);

        f32x4 rt = z4;
        if (anyPos) {
            float4 cb = s_box[chosen];
            float sx = ((float)x + 0.5f) * stride;    // exact
            float sy = ((float)y + 0.5f) * stride;
            rt.x = (sx - cb.x) * 0.25f;
            rt.y = (sy - cb.y) * 0.25f;
            rt.z = (cb.z - sx) * 0.25f;
            rt.w = (cb.w - sy) * 0.25f;
            // sparse one-hot scatter; ordered after the zero-fill by the
            // vmcnt(0)-draining __syncthreads above.
            __builtin_nontemporal_store(1.0f,
                &out[(imgBase + p) * 80 + s_lab[chosen]]);
        }
        __builtin_nontemporal_store(rt,
            &((f32x4*)out)[(size_t)REGT_OFF / 4 + imgBase + p]);
    }

    // ---- 4. num_pos: per-wave ballot + one float atomic per wave.
    unsigned long long bal = __ballot(active && anyPos);
    if ((tid & 63) == 0) {
        int c = __popcll(bal);
        if (c) atomicAdd(out + NUMP_OFF + img, (float)c);
    }
}

extern "C" void kernel_launch(void* const* d_in, const int* in_sizes, int n_in,
                              void* d_out, int out_size, void* d_ws, size_t ws_size,
                              hipStream_t stream) {
    const int*   levels = (const int*)d_in[0];    // (16,64) int32
    const float* gt     = (const float*)d_in[1];  // (16,64,5) f32
    float*       out    = (float*)d_out;

    // zero the 16 num_pos accumulators only (64 B — negligible node)
    (void)hipMemsetAsync((char*)d_out + (size_t)NUMP_OFF * sizeof(float), 0,
                         BATCH * sizeof(float), stream);

    dim3 grid(86, BATCH);
    fsaf_kernel<<<grid, 256, 0, stream>>>(levels, gt, out);
}